// Round 5
// baseline (164.219 us; speedup 1.0000x reference)
//
#include <hip/hip_runtime.h>
#include <hip/hip_bf16.h>

#define NSAMP 128
#define AGENTS 64
#define D 128
#define NN (NSAMP * AGENTS)      // 8192
#define LOG2E 1.44269504088896340736f
#define LN2   0.69314718055994530942f
#define EPSF  1e-5f

typedef __attribute__((ext_vector_type(8))) short short8;
typedef __attribute__((ext_vector_type(4))) float floatx4;

__device__ __forceinline__ float u2f(unsigned v) {
    float f; __builtin_memcpy(&f, &v, 4); return f;
}
__device__ __forceinline__ unsigned f2u(float f) {
    unsigned v; __builtin_memcpy(&v, &f, 4); return v;
}
__device__ __forceinline__ unsigned short f2bf(float f) {
    unsigned x; __builtin_memcpy(&x, &f, 4);
    return (unsigned short)((x + 0x7FFFu + ((x >> 16) & 1u)) >> 16);
}

// ---------------------------------------------------------------------------
// K0: build transposed bf16 weights WT[layer][arr][c][k] = Wside[k][c];
//     arr: 0=Af(dst) 1=Bf(src) 2=As(dst) 3=Bs(src).  Zero sacc (both layers).
// grid 65: 0..63 weights, 64 zeros sacc.
// ---------------------------------------------------------------------------
__global__ __launch_bounds__(256) void cvt_kernel(
    const float* __restrict__ Wf1, const float* __restrict__ Ws1,
    const float* __restrict__ Wf2, const float* __restrict__ Ws2,
    unsigned short* __restrict__ WT, float* __restrict__ sacc)
{
    int b = blockIdx.x;
    if (b < 64) {
        int rr = b * 16 + (threadIdx.x >> 4);   // layer*512 + arr*128 + c
        int kk = (threadIdx.x & 15) * 8;
        int layer = rr >> 9, rem = rr & 511, arr = rem >> 7, c = rem & 127;
        const float* M = (arr < 2) ? (layer ? Wf2 : Wf1) : (layer ? Ws2 : Ws1);
        int side = arr & 1;
        short8 s;
        #pragma unroll
        for (int j = 0; j < 8; ++j)
            s[j] = (short)f2bf(M[(size_t)(side * 128 + kk + j) * D + c]);
        *(short8*)&WT[(size_t)(layer * 4 + arr) * 16384 + c * 128 + kk] = s;
    } else {
        sacc[threadIdx.x]       = 0.f;
        sacc[256 + threadIdx.x] = 0.f;
    }
}

// Per-block slot-tree reduce of (s1,s2), then one atomicAdd per (stat, col).
__device__ __forceinline__ void stats_tree(
    unsigned int (*EApk)[17], unsigned int (*EBpk)[17],
    int cl, int slot, int c, float s1, float s2, float* __restrict__ sc)
{
    __syncthreads();                         // all gate reads done; reuse LDS
    EApk[slot][cl] = f2u(s1);
    EBpk[slot][cl] = f2u(s2);
    __syncthreads();
    #pragma unroll
    for (int off = 8; off >= 1; off >>= 1) {
        if (slot < off) {
            EApk[slot][cl] = f2u(u2f(EApk[slot][cl]) + u2f(EApk[slot + off][cl]));
            EBpk[slot][cl] = f2u(u2f(EBpk[slot][cl]) + u2f(EBpk[slot + off][cl]));
        }
        __syncthreads();
    }
    if (slot == 0) {
        atomicAdd(&sc[c],       u2f(EApk[0][cl]));
        atomicAdd(&sc[128 + c], u2f(EBpk[0][cl]));
    }
}

// ---------------------------------------------------------------------------
// K1/K2: half-sample prep. Logical block = (s, q, h): EA gates for 32 dst
// rows (h half), EB gates for all 64 src rows; phaseB = 2 dst rows/thread.
// XCD SWIZZLE: with round-robin blockIdx%8 -> XCD dispatch, map all 16
// blocks of sample s onto XCD s%8 so the sample's x rows are fetched into
// one L2 once (was: scattered across 8 XCDs -> 8x redundant HBM traffic,
// FETCH_SIZE 36.5 MB vs 4.5 MB ideal).  Same mapping both layers so layer-2
// reads of agg1/x0 hit the same XCD's L2 (16 samples/XCD x 64KB ~ 1MB < 4MB).
// ---------------------------------------------------------------------------
template<int LAYER>
__global__ __launch_bounds__(256, 8) void prep_half(
    const float* __restrict__ xin,           // x0
    const float* __restrict__ agg_in,        // LAYER==2: agg1
    const unsigned short* __restrict__ WT,   // this layer's [4][128][128] bf16
    const float* __restrict__ centers,
    const float* __restrict__ Wf, const float* __restrict__ bf_,
    const float* __restrict__ Ws, const float* __restrict__ bs_,
    const float* __restrict__ gm_prev, const float* __restrict__ bt_prev,
    const float* __restrict__ sacc_prev,     // LAYER==2: layer-1 raw sums
    float* __restrict__ agg_out, float* __restrict__ sacc_out)
{
    // Swizzled decode: bid = xcd + 8*(inner + 16*sHigh); s = sHigh*8 + xcd.
    const int bid = blockIdx.x;
    const int xcd = bid & 7;
    const int tmp = bid >> 3;
    const int inner = tmp & 15;              // q*2 + h
    const int s = ((tmp >> 4) << 3) + xcd;
    const int q = inner >> 1, h = inner & 1;

    const int nbase = s * AGENTS;
    const int tid = threadIdx.x, w = tid >> 6, lane = tid & 63;
    const int quad = lane >> 4, l16 = lane & 15;
    const int col = q * 16 + l16;

    __shared__ unsigned int EApk[32][17];    // local dst rows (h half)
    __shared__ unsigned int EBpk[64][17];    // all src rows
    __shared__ float bnA[128], bnB[128];     // LAYER==2 only

    if (LAYER == 2) {
        if (tid < 128) {
            const float inv = 1.f / NN;
            float mu = sacc_prev[tid] * inv;
            float var = sacc_prev[128 + tid] * inv - mu * mu;
            float rs = rsqrtf(var + EPSF);
            float A = rs * gm_prev[tid];
            bnA[tid] = A;
            bnB[tid] = fmaf(-mu, A, bt_prev[tid]);
        }
        __syncthreads();
    }

    // ---- Phase A: A-fragments for this wave's 16 rows ----
    short8 a[4];
    if (LAYER == 1) {
        const float* xr = xin + (size_t)(nbase + w * 16 + l16) * D + quad * 8;
        #pragma unroll
        for (int kc = 0; kc < 4; ++kc) {
            float4 v0 = *(const float4*)(xr + kc * 32);
            float4 v1 = *(const float4*)(xr + kc * 32 + 4);
            short8 t;
            t[0] = (short)f2bf(v0.x); t[1] = (short)f2bf(v0.y);
            t[2] = (short)f2bf(v0.z); t[3] = (short)f2bf(v0.w);
            t[4] = (short)f2bf(v1.x); t[5] = (short)f2bf(v1.y);
            t[6] = (short)f2bf(v1.z); t[7] = (short)f2bf(v1.w);
            a[kc] = t;
        }
    } else {
        // x1 on the fly: relu(agg1*A + B + x0)   (verified math)
        const size_t ro = (size_t)(nbase + w * 16 + l16) * D + quad * 8;
        #pragma unroll
        for (int kc = 0; kc < 4; ++kc) {
            int cc = quad * 8 + kc * 32;
            float4 g0 = *(const float4*)&agg_in[ro + kc * 32];
            float4 g1 = *(const float4*)&agg_in[ro + kc * 32 + 4];
            float4 x0v = *(const float4*)(xin + ro + kc * 32);
            float4 x1v = *(const float4*)(xin + ro + kc * 32 + 4);
            float4 A0 = *(const float4*)&bnA[cc], A1 = *(const float4*)&bnA[cc + 4];
            float4 B0 = *(const float4*)&bnB[cc], B1 = *(const float4*)&bnB[cc + 4];
            short8 t;
            t[0] = (short)f2bf(fmaxf(0.f, fmaf(g0.x, A0.x, B0.x) + x0v.x));
            t[1] = (short)f2bf(fmaxf(0.f, fmaf(g0.y, A0.y, B0.y) + x0v.y));
            t[2] = (short)f2bf(fmaxf(0.f, fmaf(g0.z, A0.z, B0.z) + x0v.z));
            t[3] = (short)f2bf(fmaxf(0.f, fmaf(g0.w, A0.w, B0.w) + x0v.w));
            t[4] = (short)f2bf(fmaxf(0.f, fmaf(g1.x, A1.x, B1.x) + x1v.x));
            t[5] = (short)f2bf(fmaxf(0.f, fmaf(g1.y, A1.y, B1.y) + x1v.y));
            t[6] = (short)f2bf(fmaxf(0.f, fmaf(g1.z, A1.z, B1.z) + x1v.z));
            t[7] = (short)f2bf(fmaxf(0.f, fmaf(g1.w, A1.w, B1.w) + x1v.w));
            a[kc] = t;
        }
    }

    // ---- MFMA: EB (arrs 1,3) for all waves; EA (arrs 0,2) if dst half ----
    const int doEA = ((w >> 1) == h);
    floatx4 accB[2];
    #pragma unroll
    for (int a2 = 0; a2 < 2; ++a2) {
        const int arr = 1 + 2 * a2;
        const unsigned short* wp = WT + ((size_t)arr * 128 + col) * 128 + quad * 8;
        floatx4 ac = {0.f, 0.f, 0.f, 0.f};
        #pragma unroll
        for (int kc = 0; kc < 4; ++kc)
            ac = __builtin_amdgcn_mfma_f32_16x16x32_bf16(
                a[kc], *(const short8*)(wp + kc * 32), ac, 0, 0, 0);
        accB[a2] = ac;
    }
    floatx4 accA[2] = {{0,0,0,0},{0,0,0,0}};
    if (doEA) {
        #pragma unroll
        for (int a2 = 0; a2 < 2; ++a2) {
            const int arr = 2 * a2;
            const unsigned short* wp = WT + ((size_t)arr * 128 + col) * 128 + quad * 8;
            floatx4 ac = {0.f, 0.f, 0.f, 0.f};
            #pragma unroll
            for (int kc = 0; kc < 4; ++kc)
                ac = __builtin_amdgcn_mfma_f32_16x16x32_bf16(
                    a[kc], *(const short8*)(wp + kc * 32), ac, 0, 0, 0);
            accA[a2] = ac;
        }
    }
    const float cwf0 = Wf[256 * D + col], cwf1 = Wf[257 * D + col];
    const float cws0 = Ws[256 * D + col], cws1 = Ws[257 * D + col];
    const float bfv = bf_[col], bsv = bs_[col];
    #pragma unroll
    for (int r = 0; r < 4; ++r) {
        int row = w * 16 + quad * 4 + r;              // 0..63 src row
        int n = nbase + row;
        float ce0 = centers[2 * n], ce1 = centers[2 * n + 1];
        float ctf = fmaf(ce0, cwf0, ce1 * cwf1);
        float cts = fmaf(ce0, cws0, ce1 * cws1);
        unsigned ebf = (unsigned)f2bf(__builtin_amdgcn_exp2f(-LOG2E * (accB[0][r] - ctf)));
        unsigned ebs = (unsigned)f2bf(__builtin_amdgcn_exp2f( LOG2E * (accB[1][r] - cts)));
        EBpk[row][l16] = ebf | (ebs << 16);
        if (doEA) {
            unsigned eaf = (unsigned)f2bf(__builtin_amdgcn_exp2f(-LOG2E * (accA[0][r] + ctf + bfv)));
            unsigned eas = (unsigned)f2bf(__builtin_amdgcn_exp2f( LOG2E * (accA[1][r] + cts + bsv)));
            EApk[(w & 1) * 16 + quad * 4 + r][l16] = eaf | (eas << 16);
        }
    }
    __syncthreads();

    // ---- Phase B: 2 dst rows per thread over all 64 src rows ----
    const int cl = tid & 15, slot = tid >> 4;
    const int c = q * 16 + cl;
    float eaf[2], eas[2], ac2[2];
    #pragma unroll
    for (int i = 0; i < 2; ++i) {
        unsigned pk = EApk[slot * 2 + i][cl];
        eaf[i] = u2f(pk << 16);
        eas[i] = u2f(pk & 0xFFFF0000u);
        ac2[i] = 0.f;
    }
    #pragma unroll 8
    for (int j = 0; j < 64; ++j) {
        unsigned pk = EBpk[j][cl];
        float ebf = u2f(pk << 16);
        float ebs = u2f(pk & 0xFFFF0000u);
        #pragma unroll
        for (int i = 0; i < 2; ++i) {
            float sg = __builtin_amdgcn_rcpf(fmaf(eaf[i], ebf, 1.f));
            float lg = __builtin_amdgcn_logf(fmaf(eas[i], ebs, 1.f));
            ac2[i] = fmaf(sg, lg, ac2[i]);
        }
    }
    float s1 = 0.f, s2 = 0.f;
    #pragma unroll
    for (int i = 0; i < 2; ++i) {
        int d = h * 32 + slot * 2 + i;                // global dst row
        unsigned pk = EBpk[d][cl];
        float ebf = u2f(pk << 16);
        float ebs = u2f(pk & 0xFFFF0000u);
        float sg = __builtin_amdgcn_rcpf(fmaf(eaf[i], ebf, 1.f));
        float lg = __builtin_amdgcn_logf(fmaf(eas[i], ebs, 1.f));
        float v = (ac2[i] - sg * lg) * LN2;           // exact self-cancel
        agg_out[(size_t)(nbase + d) * D + c] = v;
        s1 += v; s2 += v * v;
    }
    stats_tree(EApk, EBpk, cl, slot, c, s1, s2, sacc_out);
}

// ---------------------------------------------------------------------------
// K3: final BN2 + residual (x1 recomputed from agg1) + relu -> out.
// grid 512, 8 elems/thread.  Swizzled so block for sample s runs on XCD s%8
// (agg1/agg2/x0 lines are already in that L2 from the prep kernels).
// ---------------------------------------------------------------------------
__global__ __launch_bounds__(256) void final_bn(
    const float* __restrict__ x0, const float* __restrict__ agg1,
    const float* __restrict__ agg2, const float* __restrict__ sacc,
    const float* __restrict__ gm1, const float* __restrict__ bt1,
    const float* __restrict__ gm2, const float* __restrict__ bt2,
    float* __restrict__ outp)
{
    const int tid = threadIdx.x;
    __shared__ float bnA[128], bnB[128], bn2A[128], bn2B[128];
    if (tid < 128) {
        const float inv = 1.f / NN;
        float mu = sacc[tid] * inv;
        float var = sacc[128 + tid] * inv - mu * mu;
        float rs = rsqrtf(var + EPSF);
        float A = rs * gm1[tid];
        bnA[tid] = A;
        bnB[tid] = fmaf(-mu, A, bt1[tid]);
        float mu2 = sacc[256 + tid] * inv;
        float var2 = sacc[384 + tid] * inv - mu2 * mu2;
        float rs2 = rsqrtf(var2 + EPSF);
        float A2 = rs2 * gm2[tid];
        bn2A[tid] = A2;
        bn2B[tid] = fmaf(-mu2, A2, bt2[tid]);
    }
    __syncthreads();
    // Swizzle: 4 blocks/sample; sample s on XCD s%8.
    const int bid = blockIdx.x;
    const int s = ((bid >> 5) << 3) + (bid & 7);
    const int inner = (bid >> 3) & 3;
    const int t = (s * 4 + inner) * 256 + tid;
    const int n = t >> 4, c8 = (t & 15) * 8;
    size_t off = (size_t)n * D + c8;
    float o[8];
    #pragma unroll
    for (int hh = 0; hh < 2; ++hh) {
        float4 g2 = *(const float4*)&agg2[off + hh * 4];
        float4 g1 = *(const float4*)&agg1[off + hh * 4];
        float4 xv = *(const float4*)&x0[off + hh * 4];
        int cc = c8 + hh * 4;
        o[hh*4+0] = fmaxf(0.f, fmaf(g2.x, bn2A[cc+0], bn2B[cc+0]) +
                    fmaxf(0.f, fmaf(g1.x, bnA[cc+0], bnB[cc+0]) + xv.x));
        o[hh*4+1] = fmaxf(0.f, fmaf(g2.y, bn2A[cc+1], bn2B[cc+1]) +
                    fmaxf(0.f, fmaf(g1.y, bnA[cc+1], bnB[cc+1]) + xv.y));
        o[hh*4+2] = fmaxf(0.f, fmaf(g2.z, bn2A[cc+2], bn2B[cc+2]) +
                    fmaxf(0.f, fmaf(g1.z, bnA[cc+2], bnB[cc+2]) + xv.z));
        o[hh*4+3] = fmaxf(0.f, fmaf(g2.w, bn2A[cc+3], bn2B[cc+3]) +
                    fmaxf(0.f, fmaf(g1.w, bnA[cc+3], bnB[cc+3]) + xv.w));
    }
    *(float4*)&outp[off]     = *(float4*)&o[0];
    *(float4*)&outp[off + 4] = *(float4*)&o[4];
}

// ---------------------------------------------------------------------------
extern "C" void kernel_launch(void* const* d_in, const int* in_sizes, int n_in,
                              void* d_out, int out_size, void* d_ws, size_t ws_size,
                              hipStream_t stream) {
    const float* x0      = (const float*)d_in[0];
    const float* centers = (const float*)d_in[1];
    // d_in[2], d_in[3]: edge lists — clique structure is deterministic, unused.
    const float* Wf1 = (const float*)d_in[4];
    const float* bf1 = (const float*)d_in[5];
    const float* Ws1 = (const float*)d_in[6];
    const float* bs1 = (const float*)d_in[7];
    const float* gm1 = (const float*)d_in[8];
    const float* bt1 = (const float*)d_in[9];
    const float* Wf2 = (const float*)d_in[10];
    const float* bf2 = (const float*)d_in[11];
    const float* Ws2 = (const float*)d_in[12];
    const float* bs2 = (const float*)d_in[13];
    const float* gm2 = (const float*)d_in[14];
    const float* bt2 = (const float*)d_in[15];

    const size_t ND = (size_t)NN * D;              // 1048576
    unsigned short* WT = (unsigned short*)d_ws;    // 2 x 65536 bf16
    float* fbase = (float*)(WT + 2 * 65536);
    float* agg1  = fbase;                          // ND
    float* agg2  = fbase + ND;                     // ND
    float* sacc  = fbase + 2 * ND;                 // 2 layers x 256
    float* outp  = (float*)d_out;

    cvt_kernel<<<dim3(65), dim3(256), 0, stream>>>(
        Wf1, Ws1, Wf2, Ws2, WT, sacc);

    prep_half<1><<<dim3(2048), dim3(256), 0, stream>>>(
        x0, agg1 /*unused*/, WT, centers, Wf1, bf1, Ws1, bs1,
        gm1 /*unused*/, bt1 /*unused*/, sacc /*unused*/, agg1, sacc);

    prep_half<2><<<dim3(2048), dim3(256), 0, stream>>>(
        x0, agg1, WT + 65536, centers, Wf2, bf2, Ws2, bs2,
        gm1, bt1, sacc, agg2, sacc + 256);

    final_bn<<<dim3(512), dim3(256), 0, stream>>>(
        x0, agg1, agg2, sacc, gm1, bt1, gm2, bt2, outp);
}

// Round 6
// 162.557 us; speedup vs baseline: 1.0102x; 1.0102x over previous
//
#include <hip/hip_runtime.h>
#include <hip/hip_bf16.h>

#define NSAMP 128
#define AGENTS 64
#define D 128
#define NN (NSAMP * AGENTS)      // 8192
#define LOG2E 1.44269504088896340736f
#define LN2   0.69314718055994530942f
#define EPSF  1e-5f

typedef __attribute__((ext_vector_type(8))) short short8;
typedef __attribute__((ext_vector_type(4))) float floatx4;

__device__ __forceinline__ float u2f(unsigned v) {
    float f; __builtin_memcpy(&f, &v, 4); return f;
}
__device__ __forceinline__ unsigned f2u(float f) {
    unsigned v; __builtin_memcpy(&v, &f, 4); return v;
}
__device__ __forceinline__ unsigned short f2bf(float f) {
    unsigned x; __builtin_memcpy(&x, &f, 4);
    return (unsigned short)((x + 0x7FFFu + ((x >> 16) & 1u)) >> 16);
}

// ---------------------------------------------------------------------------
// K0: build transposed bf16 weights WT[layer][arr][c][k] = Wside[k][c];
//     arr: 0=Af(dst) 1=Bf(src) 2=As(dst) 3=Bs(src).  Zero sacc (both layers).
// ---------------------------------------------------------------------------
__global__ __launch_bounds__(256) void cvt_kernel(
    const float* __restrict__ Wf1, const float* __restrict__ Ws1,
    const float* __restrict__ Wf2, const float* __restrict__ Ws2,
    unsigned short* __restrict__ WT, float* __restrict__ sacc)
{
    int b = blockIdx.x;
    if (b < 64) {
        int rr = b * 16 + (threadIdx.x >> 4);   // layer*512 + arr*128 + c
        int kk = (threadIdx.x & 15) * 8;
        int layer = rr >> 9, rem = rr & 511, arr = rem >> 7, c = rem & 127;
        const float* M = (arr < 2) ? (layer ? Wf2 : Wf1) : (layer ? Ws2 : Ws1);
        int side = arr & 1;
        short8 s;
        #pragma unroll
        for (int j = 0; j < 8; ++j)
            s[j] = (short)f2bf(M[(size_t)(side * 128 + kk + j) * D + c]);
        *(short8*)&WT[(size_t)(layer * 4 + arr) * 16384 + c * 128 + kk] = s;
    } else {
        sacc[threadIdx.x]       = 0.f;
        sacc[256 + threadIdx.x] = 0.f;
    }
}

// Per-block slot-tree reduce of (s1,s2), then one atomicAdd per (stat, col).
__device__ __forceinline__ void stats_tree(
    unsigned int (*EApk)[17], unsigned int (*EBpk)[17],
    int cl, int slot, int c, float s1, float s2, float* __restrict__ sc)
{
    __syncthreads();                         // all gate reads done; reuse LDS
    EApk[slot][cl] = f2u(s1);
    EBpk[slot][cl] = f2u(s2);
    __syncthreads();
    #pragma unroll
    for (int off = 8; off >= 1; off >>= 1) {
        if (slot < off) {
            EApk[slot][cl] = f2u(u2f(EApk[slot][cl]) + u2f(EApk[slot + off][cl]));
            EBpk[slot][cl] = f2u(u2f(EBpk[slot][cl]) + u2f(EBpk[slot + off][cl]));
        }
        __syncthreads();
    }
    if (slot == 0) {
        atomicAdd(&sc[c],       u2f(EApk[0][cl]));
        atomicAdd(&sc[128 + c], u2f(EBpk[0][cl]));
    }
}

// ---------------------------------------------------------------------------
// K1/K2: half-sample prep. Logical block = (s, q, h).  XCD swizzle keeps all
// 16 blocks of sample s on XCD s%8 (verified: FETCH 36.5->5.7 MB).
// __launch_bounds__(256,4): VGPR budget 128 (was 64 -> compiler used 32 and
// couldn't pipeline the 256 rcp/log chains per thread -> 63% stall).
// Phase B batched 8 j/iter: 32 independent trans chains in flight.
// ---------------------------------------------------------------------------
template<int LAYER>
__global__ __launch_bounds__(256, 4) void prep_half(
    const float* __restrict__ xin,           // x0
    const float* __restrict__ agg_in,        // LAYER==2: agg1
    const unsigned short* __restrict__ WT,   // this layer's [4][128][128] bf16
    const float* __restrict__ centers,
    const float* __restrict__ Wf, const float* __restrict__ bf_,
    const float* __restrict__ Ws, const float* __restrict__ bs_,
    const float* __restrict__ gm_prev, const float* __restrict__ bt_prev,
    const float* __restrict__ sacc_prev,     // LAYER==2: layer-1 raw sums
    float* __restrict__ agg_out, float* __restrict__ sacc_out)
{
    // Swizzled decode: bid = xcd + 8*(inner + 16*sHigh); s = sHigh*8 + xcd.
    const int bid = blockIdx.x;
    const int xcd = bid & 7;
    const int tmp = bid >> 3;
    const int inner = tmp & 15;              // q*2 + h
    const int s = ((tmp >> 4) << 3) + xcd;
    const int q = inner >> 1, h = inner & 1;

    const int nbase = s * AGENTS;
    const int tid = threadIdx.x, w = tid >> 6, lane = tid & 63;
    const int quad = lane >> 4, l16 = lane & 15;
    const int col = q * 16 + l16;

    __shared__ unsigned int EApk[32][17];    // local dst rows (h half)
    __shared__ unsigned int EBpk[64][17];    // all src rows
    __shared__ float bnA[128], bnB[128];     // LAYER==2 only

    if (LAYER == 2) {
        if (tid < 128) {
            const float inv = 1.f / NN;
            float mu = sacc_prev[tid] * inv;
            float var = sacc_prev[128 + tid] * inv - mu * mu;
            float rs = rsqrtf(var + EPSF);
            float A = rs * gm_prev[tid];
            bnA[tid] = A;
            bnB[tid] = fmaf(-mu, A, bt_prev[tid]);
        }
        __syncthreads();
    }

    // ---- Phase A: A-fragments for this wave's 16 rows ----
    short8 a[4];
    if (LAYER == 1) {
        const float* xr = xin + (size_t)(nbase + w * 16 + l16) * D + quad * 8;
        #pragma unroll
        for (int kc = 0; kc < 4; ++kc) {
            float4 v0 = *(const float4*)(xr + kc * 32);
            float4 v1 = *(const float4*)(xr + kc * 32 + 4);
            short8 t;
            t[0] = (short)f2bf(v0.x); t[1] = (short)f2bf(v0.y);
            t[2] = (short)f2bf(v0.z); t[3] = (short)f2bf(v0.w);
            t[4] = (short)f2bf(v1.x); t[5] = (short)f2bf(v1.y);
            t[6] = (short)f2bf(v1.z); t[7] = (short)f2bf(v1.w);
            a[kc] = t;
        }
    } else {
        // x1 on the fly: relu(agg1*A + B + x0)   (verified math)
        const size_t ro = (size_t)(nbase + w * 16 + l16) * D + quad * 8;
        #pragma unroll
        for (int kc = 0; kc < 4; ++kc) {
            int cc = quad * 8 + kc * 32;
            float4 g0 = *(const float4*)&agg_in[ro + kc * 32];
            float4 g1 = *(const float4*)&agg_in[ro + kc * 32 + 4];
            float4 x0v = *(const float4*)(xin + ro + kc * 32);
            float4 x1v = *(const float4*)(xin + ro + kc * 32 + 4);
            float4 A0 = *(const float4*)&bnA[cc], A1 = *(const float4*)&bnA[cc + 4];
            float4 B0 = *(const float4*)&bnB[cc], B1 = *(const float4*)&bnB[cc + 4];
            short8 t;
            t[0] = (short)f2bf(fmaxf(0.f, fmaf(g0.x, A0.x, B0.x) + x0v.x));
            t[1] = (short)f2bf(fmaxf(0.f, fmaf(g0.y, A0.y, B0.y) + x0v.y));
            t[2] = (short)f2bf(fmaxf(0.f, fmaf(g0.z, A0.z, B0.z) + x0v.z));
            t[3] = (short)f2bf(fmaxf(0.f, fmaf(g0.w, A0.w, B0.w) + x0v.w));
            t[4] = (short)f2bf(fmaxf(0.f, fmaf(g1.x, A1.x, B1.x) + x1v.x));
            t[5] = (short)f2bf(fmaxf(0.f, fmaf(g1.y, A1.y, B1.y) + x1v.y));
            t[6] = (short)f2bf(fmaxf(0.f, fmaf(g1.z, A1.z, B1.z) + x1v.z));
            t[7] = (short)f2bf(fmaxf(0.f, fmaf(g1.w, A1.w, B1.w) + x1v.w));
            a[kc] = t;
        }
    }

    // ---- MFMA: EB (arrs 1,3) for all waves; EA (arrs 0,2) if dst half ----
    const int doEA = ((w >> 1) == h);
    floatx4 accB[2];
    #pragma unroll
    for (int a2 = 0; a2 < 2; ++a2) {
        const int arr = 1 + 2 * a2;
        const unsigned short* wp = WT + ((size_t)arr * 128 + col) * 128 + quad * 8;
        floatx4 ac = {0.f, 0.f, 0.f, 0.f};
        #pragma unroll
        for (int kc = 0; kc < 4; ++kc)
            ac = __builtin_amdgcn_mfma_f32_16x16x32_bf16(
                a[kc], *(const short8*)(wp + kc * 32), ac, 0, 0, 0);
        accB[a2] = ac;
    }
    floatx4 accA[2] = {{0,0,0,0},{0,0,0,0}};
    if (doEA) {
        #pragma unroll
        for (int a2 = 0; a2 < 2; ++a2) {
            const int arr = 2 * a2;
            const unsigned short* wp = WT + ((size_t)arr * 128 + col) * 128 + quad * 8;
            floatx4 ac = {0.f, 0.f, 0.f, 0.f};
            #pragma unroll
            for (int kc = 0; kc < 4; ++kc)
                ac = __builtin_amdgcn_mfma_f32_16x16x32_bf16(
                    a[kc], *(const short8*)(wp + kc * 32), ac, 0, 0, 0);
            accA[a2] = ac;
        }
    }
    const float cwf0 = Wf[256 * D + col], cwf1 = Wf[257 * D + col];
    const float cws0 = Ws[256 * D + col], cws1 = Ws[257 * D + col];
    const float bfv = bf_[col], bsv = bs_[col];
    #pragma unroll
    for (int r = 0; r < 4; ++r) {
        int row = w * 16 + quad * 4 + r;              // 0..63 src row
        int n = nbase + row;
        float ce0 = centers[2 * n], ce1 = centers[2 * n + 1];
        float ctf = fmaf(ce0, cwf0, ce1 * cwf1);
        float cts = fmaf(ce0, cws0, ce1 * cws1);
        unsigned ebf = (unsigned)f2bf(__builtin_amdgcn_exp2f(-LOG2E * (accB[0][r] - ctf)));
        unsigned ebs = (unsigned)f2bf(__builtin_amdgcn_exp2f( LOG2E * (accB[1][r] - cts)));
        EBpk[row][l16] = ebf | (ebs << 16);
        if (doEA) {
            unsigned eaf = (unsigned)f2bf(__builtin_amdgcn_exp2f(-LOG2E * (accA[0][r] + ctf + bfv)));
            unsigned eas = (unsigned)f2bf(__builtin_amdgcn_exp2f( LOG2E * (accA[1][r] + cts + bsv)));
            EApk[(w & 1) * 16 + quad * 4 + r][l16] = eaf | (eas << 16);
        }
    }
    __syncthreads();

    // ---- Phase B: 2 dst rows/thread, 8-j batches for deep trans pipelining ----
    const int cl = tid & 15, slot = tid >> 4;
    const int c = q * 16 + cl;
    float eaf[2], eas[2], ac2[2];
    #pragma unroll
    for (int i = 0; i < 2; ++i) {
        unsigned pk = EApk[slot * 2 + i][cl];
        eaf[i] = u2f(pk << 16);
        eas[i] = u2f(pk & 0xFFFF0000u);
        ac2[i] = 0.f;
    }
    #pragma unroll
    for (int jb = 0; jb < 64; jb += 8) {
        float ebf[8], ebs[8];
        #pragma unroll
        for (int u = 0; u < 8; ++u) {
            unsigned pk = EBpk[jb + u][cl];
            ebf[u] = u2f(pk << 16);
            ebs[u] = u2f(pk & 0xFFFF0000u);
        }
        float sg[16], lg[16];
        #pragma unroll
        for (int u = 0; u < 8; ++u) {
            sg[u * 2 + 0] = __builtin_amdgcn_rcpf(fmaf(eaf[0], ebf[u], 1.f));
            sg[u * 2 + 1] = __builtin_amdgcn_rcpf(fmaf(eaf[1], ebf[u], 1.f));
            lg[u * 2 + 0] = __builtin_amdgcn_logf(fmaf(eas[0], ebs[u], 1.f));
            lg[u * 2 + 1] = __builtin_amdgcn_logf(fmaf(eas[1], ebs[u], 1.f));
        }
        #pragma unroll
        for (int u = 0; u < 8; ++u) {
            ac2[0] = fmaf(sg[u * 2 + 0], lg[u * 2 + 0], ac2[0]);
            ac2[1] = fmaf(sg[u * 2 + 1], lg[u * 2 + 1], ac2[1]);
        }
    }
    float s1 = 0.f, s2 = 0.f;
    #pragma unroll
    for (int i = 0; i < 2; ++i) {
        int d = h * 32 + slot * 2 + i;                // global dst row
        unsigned pk = EBpk[d][cl];
        float ebf = u2f(pk << 16);
        float ebs = u2f(pk & 0xFFFF0000u);
        float sg = __builtin_amdgcn_rcpf(fmaf(eaf[i], ebf, 1.f));
        float lg = __builtin_amdgcn_logf(fmaf(eas[i], ebs, 1.f));
        float v = (ac2[i] - sg * lg) * LN2;           // exact self-cancel
        agg_out[(size_t)(nbase + d) * D + c] = v;
        s1 += v; s2 += v * v;
    }
    stats_tree(EApk, EBpk, cl, slot, c, s1, s2, sacc_out);
}

// ---------------------------------------------------------------------------
// K3: final BN2 + residual (x1 recomputed from agg1) + relu -> out.
// Swizzled so the block for sample s runs on XCD s%8.
// ---------------------------------------------------------------------------
__global__ __launch_bounds__(256) void final_bn(
    const float* __restrict__ x0, const float* __restrict__ agg1,
    const float* __restrict__ agg2, const float* __restrict__ sacc,
    const float* __restrict__ gm1, const float* __restrict__ bt1,
    const float* __restrict__ gm2, const float* __restrict__ bt2,
    float* __restrict__ outp)
{
    const int tid = threadIdx.x;
    __shared__ float bnA[128], bnB[128], bn2A[128], bn2B[128];
    if (tid < 128) {
        const float inv = 1.f / NN;
        float mu = sacc[tid] * inv;
        float var = sacc[128 + tid] * inv - mu * mu;
        float rs = rsqrtf(var + EPSF);
        float A = rs * gm1[tid];
        bnA[tid] = A;
        bnB[tid] = fmaf(-mu, A, bt1[tid]);
        float mu2 = sacc[256 + tid] * inv;
        float var2 = sacc[384 + tid] * inv - mu2 * mu2;
        float rs2 = rsqrtf(var2 + EPSF);
        float A2 = rs2 * gm2[tid];
        bn2A[tid] = A2;
        bn2B[tid] = fmaf(-mu2, A2, bt2[tid]);
    }
    __syncthreads();
    const int bid = blockIdx.x;
    const int s = ((bid >> 5) << 3) + (bid & 7);
    const int inner = (bid >> 3) & 3;
    const int t = (s * 4 + inner) * 256 + tid;
    const int n = t >> 4, c8 = (t & 15) * 8;
    size_t off = (size_t)n * D + c8;
    float o[8];
    #pragma unroll
    for (int hh = 0; hh < 2; ++hh) {
        float4 g2 = *(const float4*)&agg2[off + hh * 4];
        float4 g1 = *(const float4*)&agg1[off + hh * 4];
        float4 xv = *(const float4*)&x0[off + hh * 4];
        int cc = c8 + hh * 4;
        o[hh*4+0] = fmaxf(0.f, fmaf(g2.x, bn2A[cc+0], bn2B[cc+0]) +
                    fmaxf(0.f, fmaf(g1.x, bnA[cc+0], bnB[cc+0]) + xv.x));
        o[hh*4+1] = fmaxf(0.f, fmaf(g2.y, bn2A[cc+1], bn2B[cc+1]) +
                    fmaxf(0.f, fmaf(g1.y, bnA[cc+1], bnB[cc+1]) + xv.y));
        o[hh*4+2] = fmaxf(0.f, fmaf(g2.z, bn2A[cc+2], bn2B[cc+2]) +
                    fmaxf(0.f, fmaf(g1.z, bnA[cc+2], bnB[cc+2]) + xv.z));
        o[hh*4+3] = fmaxf(0.f, fmaf(g2.w, bn2A[cc+3], bn2B[cc+3]) +
                    fmaxf(0.f, fmaf(g1.w, bnA[cc+3], bnB[cc+3]) + xv.w));
    }
    *(float4*)&outp[off]     = *(float4*)&o[0];
    *(float4*)&outp[off + 4] = *(float4*)&o[4];
}

// ---------------------------------------------------------------------------
extern "C" void kernel_launch(void* const* d_in, const int* in_sizes, int n_in,
                              void* d_out, int out_size, void* d_ws, size_t ws_size,
                              hipStream_t stream) {
    const float* x0      = (const float*)d_in[0];
    const float* centers = (const float*)d_in[1];
    // d_in[2], d_in[3]: edge lists — clique structure is deterministic, unused.
    const float* Wf1 = (const float*)d_in[4];
    const float* bf1 = (const float*)d_in[5];
    const float* Ws1 = (const float*)d_in[6];
    const float* bs1 = (const float*)d_in[7];
    const float* gm1 = (const float*)d_in[8];
    const float* bt1 = (const float*)d_in[9];
    const float* Wf2 = (const float*)d_in[10];
    const float* bf2 = (const float*)d_in[11];
    const float* Ws2 = (const float*)d_in[12];
    const float* bs2 = (const float*)d_in[13];
    const float* gm2 = (const float*)d_in[14];
    const float* bt2 = (const float*)d_in[15];

    const size_t ND = (size_t)NN * D;              // 1048576
    unsigned short* WT = (unsigned short*)d_ws;    // 2 x 65536 bf16
    float* fbase = (float*)(WT + 2 * 65536);
    float* agg1  = fbase;                          // ND
    float* agg2  = fbase + ND;                     // ND
    float* sacc  = fbase + 2 * ND;                 // 2 layers x 256
    float* outp  = (float*)d_out;

    cvt_kernel<<<dim3(65), dim3(256), 0, stream>>>(
        Wf1, Ws1, Wf2, Ws2, WT, sacc);

    prep_half<1><<<dim3(2048), dim3(256), 0, stream>>>(
        x0, agg1 /*unused*/, WT, centers, Wf1, bf1, Ws1, bs1,
        gm1 /*unused*/, bt1 /*unused*/, sacc /*unused*/, agg1, sacc);

    prep_half<2><<<dim3(2048), dim3(256), 0, stream>>>(
        x0, agg1, WT + 65536, centers, Wf2, bf2, Ws2, bs2,
        gm1, bt1, sacc, agg2, sacc + 256);

    final_bn<<<dim3(512), dim3(256), 0, stream>>>(
        x0, agg1, agg2, sacc, gm1, bt1, gm2, bt2, outp);
}

// Round 7
// 150.498 us; speedup vs baseline: 1.0912x; 1.0801x over previous
//
#include <hip/hip_runtime.h>
#include <hip/hip_bf16.h>

#define NSAMP 128
#define AGENTS 64
#define D 128
#define NN (NSAMP * AGENTS)      // 8192
#define LOG2E 1.44269504088896340736f
#define LN2   0.69314718055994530942f
#define EPSF  1e-5f

typedef __attribute__((ext_vector_type(8))) short short8;
typedef __attribute__((ext_vector_type(4))) float floatx4;

__device__ __forceinline__ float u2f(unsigned v) {
    float f; __builtin_memcpy(&f, &v, 4); return f;
}
__device__ __forceinline__ unsigned f2u(float f) {
    unsigned v; __builtin_memcpy(&v, &f, 4); return v;
}
__device__ __forceinline__ unsigned short f2bf(float f) {
    unsigned x; __builtin_memcpy(&x, &f, 4);
    return (unsigned short)((x + 0x7FFFu + ((x >> 16) & 1u)) >> 16);
}

// Per-block slot-tree reduce of (s1,s2), then one atomicAdd per (stat, col).
__device__ __forceinline__ void stats_tree(
    unsigned int (*EApk)[17], unsigned int (*EBpk)[17],
    int cl, int slot, int c, float s1, float s2, float* __restrict__ sc)
{
    __syncthreads();                         // all gate reads done; reuse LDS
    EApk[slot][cl] = f2u(s1);
    EBpk[slot][cl] = f2u(s2);
    __syncthreads();
    #pragma unroll
    for (int off = 8; off >= 1; off >>= 1) {
        if (slot < off) {
            EApk[slot][cl] = f2u(u2f(EApk[slot][cl]) + u2f(EApk[slot + off][cl]));
            EBpk[slot][cl] = f2u(u2f(EBpk[slot][cl]) + u2f(EBpk[slot + off][cl]));
        }
        __syncthreads();
    }
    if (slot == 0) {
        atomicAdd(&sc[c],       u2f(EApk[0][cl]));
        atomicAdd(&sc[128 + c], u2f(EBpk[0][cl]));
    }
}

// ---------------------------------------------------------------------------
// prep_half: block = (s, q, h).  XCD swizzle: sample s -> XCD s%8 (verified).
// Weights self-converted into LDS WL (replaces cvt kernel; stride 136 shorts
// -> odd 16B-slot stride -> 2-way-free ds_read_b128 B-frags).
// Phase B: volatile-asm trans batches (32 rcp/log in flight) to force ILP.
// ---------------------------------------------------------------------------
template<int LAYER>
__global__ __launch_bounds__(256, 4) void prep_half(
    const float* __restrict__ xin,           // x0
    const float* __restrict__ agg_in,        // LAYER==2: agg1
    const float* __restrict__ centers,
    const float* __restrict__ Wf, const float* __restrict__ bf_,
    const float* __restrict__ Ws, const float* __restrict__ bs_,
    const float* __restrict__ gm_prev, const float* __restrict__ bt_prev,
    const float* __restrict__ sacc_prev,     // LAYER==2: layer-1 raw sums
    float* __restrict__ agg_out, float* __restrict__ sacc_out)
{
    // Swizzled decode: bid = xcd + 8*(inner + 16*sHigh); s = sHigh*8 + xcd.
    const int bid = blockIdx.x;
    const int xcd = bid & 7;
    const int tmp = bid >> 3;
    const int inner = tmp & 15;              // q*2 + h
    const int s = ((tmp >> 4) << 3) + xcd;
    const int q = inner >> 1, h = inner & 1;

    const int nbase = s * AGENTS;
    const int tid = threadIdx.x, w = tid >> 6, lane = tid & 63;
    const int quad = lane >> 4, l16 = lane & 15;
    const int col = q * 16 + l16;

    __shared__ __align__(16) unsigned short WL[4][16][136]; // arr, col16, k
    __shared__ unsigned int EApk[32][17];    // local dst rows (h half)
    __shared__ unsigned int EBpk[64][17];    // all src rows
    __shared__ float bnA[128], bnB[128];     // LAYER==2 only

    // ---- weight slice fp32 -> bf16 into LDS (replaces cvt kernel) ----
    {
        const int arr = tid >> 6, klane = tid & 63;
        const int wcol = klane & 15, kg = klane >> 4;   // k-group of 32
        const float* M = (arr < 2) ? Wf : Ws;
        const int side = arr & 1;
        const float* src = M + (size_t)(side * 128 + kg * 32) * D + q * 16 + wcol;
        #pragma unroll
        for (int u = 0; u < 16; ++u) {
            float f0 = src[(size_t)(2 * u) * D];
            float f1 = src[(size_t)(2 * u + 1) * D];
            unsigned pk = (unsigned)f2bf(f0) | ((unsigned)f2bf(f1) << 16);
            *(unsigned*)&WL[arr][wcol][kg * 32 + 2 * u] = pk;
        }
    }
    if (LAYER == 2) {
        if (tid < 128) {
            const float inv = 1.f / NN;
            float mu = sacc_prev[tid] * inv;
            float var = sacc_prev[128 + tid] * inv - mu * mu;
            float rs = rsqrtf(var + EPSF);
            float A = rs * gm_prev[tid];
            bnA[tid] = A;
            bnB[tid] = fmaf(-mu, A, bt_prev[tid]);
        }
    }
    __syncthreads();   // WL (and bnA/bnB) ready

    // ---- Phase A: A-fragments for this wave's 16 rows ----
    short8 a[4];
    if (LAYER == 1) {
        const float* xr = xin + (size_t)(nbase + w * 16 + l16) * D + quad * 8;
        #pragma unroll
        for (int kc = 0; kc < 4; ++kc) {
            float4 v0 = *(const float4*)(xr + kc * 32);
            float4 v1 = *(const float4*)(xr + kc * 32 + 4);
            short8 t;
            t[0] = (short)f2bf(v0.x); t[1] = (short)f2bf(v0.y);
            t[2] = (short)f2bf(v0.z); t[3] = (short)f2bf(v0.w);
            t[4] = (short)f2bf(v1.x); t[5] = (short)f2bf(v1.y);
            t[6] = (short)f2bf(v1.z); t[7] = (short)f2bf(v1.w);
            a[kc] = t;
        }
    } else {
        // x1 on the fly: relu(agg1*A + B + x0)   (verified math)
        const size_t ro = (size_t)(nbase + w * 16 + l16) * D + quad * 8;
        #pragma unroll
        for (int kc = 0; kc < 4; ++kc) {
            int cc = quad * 8 + kc * 32;
            float4 g0 = *(const float4*)&agg_in[ro + kc * 32];
            float4 g1 = *(const float4*)&agg_in[ro + kc * 32 + 4];
            float4 x0v = *(const float4*)(xin + ro + kc * 32);
            float4 x1v = *(const float4*)(xin + ro + kc * 32 + 4);
            float4 A0 = *(const float4*)&bnA[cc], A1 = *(const float4*)&bnA[cc + 4];
            float4 B0 = *(const float4*)&bnB[cc], B1 = *(const float4*)&bnB[cc + 4];
            short8 t;
            t[0] = (short)f2bf(fmaxf(0.f, fmaf(g0.x, A0.x, B0.x) + x0v.x));
            t[1] = (short)f2bf(fmaxf(0.f, fmaf(g0.y, A0.y, B0.y) + x0v.y));
            t[2] = (short)f2bf(fmaxf(0.f, fmaf(g0.z, A0.z, B0.z) + x0v.z));
            t[3] = (short)f2bf(fmaxf(0.f, fmaf(g0.w, A0.w, B0.w) + x0v.w));
            t[4] = (short)f2bf(fmaxf(0.f, fmaf(g1.x, A1.x, B1.x) + x1v.x));
            t[5] = (short)f2bf(fmaxf(0.f, fmaf(g1.y, A1.y, B1.y) + x1v.y));
            t[6] = (short)f2bf(fmaxf(0.f, fmaf(g1.z, A1.z, B1.z) + x1v.z));
            t[7] = (short)f2bf(fmaxf(0.f, fmaf(g1.w, A1.w, B1.w) + x1v.w));
            a[kc] = t;
        }
    }

    // ---- MFMA: EB (arrs 1,3) for all waves; EA (arrs 0,2) if dst half ----
    const int doEA = ((w >> 1) == h);
    floatx4 accB[2];
    #pragma unroll
    for (int a2 = 0; a2 < 2; ++a2) {
        const int arr = 1 + 2 * a2;
        floatx4 ac = {0.f, 0.f, 0.f, 0.f};
        #pragma unroll
        for (int kc = 0; kc < 4; ++kc)
            ac = __builtin_amdgcn_mfma_f32_16x16x32_bf16(
                a[kc], *(const short8*)&WL[arr][l16][quad * 8 + kc * 32], ac, 0, 0, 0);
        accB[a2] = ac;
    }
    floatx4 accA[2] = {{0,0,0,0},{0,0,0,0}};
    if (doEA) {
        #pragma unroll
        for (int a2 = 0; a2 < 2; ++a2) {
            const int arr = 2 * a2;
            floatx4 ac = {0.f, 0.f, 0.f, 0.f};
            #pragma unroll
            for (int kc = 0; kc < 4; ++kc)
                ac = __builtin_amdgcn_mfma_f32_16x16x32_bf16(
                    a[kc], *(const short8*)&WL[arr][l16][quad * 8 + kc * 32], ac, 0, 0, 0);
            accA[a2] = ac;
        }
    }
    const float cwf0 = Wf[256 * D + col], cwf1 = Wf[257 * D + col];
    const float cws0 = Ws[256 * D + col], cws1 = Ws[257 * D + col];
    const float bfv = bf_[col], bsv = bs_[col];
    #pragma unroll
    for (int r = 0; r < 4; ++r) {
        int row = w * 16 + quad * 4 + r;              // 0..63 src row
        int n = nbase + row;
        float ce0 = centers[2 * n], ce1 = centers[2 * n + 1];
        float ctf = fmaf(ce0, cwf0, ce1 * cwf1);
        float cts = fmaf(ce0, cws0, ce1 * cws1);
        unsigned ebf = (unsigned)f2bf(__builtin_amdgcn_exp2f(-LOG2E * (accB[0][r] - ctf)));
        unsigned ebs = (unsigned)f2bf(__builtin_amdgcn_exp2f( LOG2E * (accB[1][r] - cts)));
        EBpk[row][l16] = ebf | (ebs << 16);
        if (doEA) {
            unsigned eaf = (unsigned)f2bf(__builtin_amdgcn_exp2f(-LOG2E * (accA[0][r] + ctf + bfv)));
            unsigned eas = (unsigned)f2bf(__builtin_amdgcn_exp2f( LOG2E * (accA[1][r] + cts + bsv)));
            EApk[(w & 1) * 16 + quad * 4 + r][l16] = eaf | (eas << 16);
        }
    }
    __syncthreads();

    // ---- Phase B: 2 dst rows/thread; volatile-asm trans batches (forced ILP) ----
    const int cl = tid & 15, slot = tid >> 4;
    const int c = q * 16 + cl;
    float eaf[2], eas[2], ac2[2];
    #pragma unroll
    for (int i = 0; i < 2; ++i) {
        unsigned pk = EApk[slot * 2 + i][cl];
        eaf[i] = u2f(pk << 16);
        eas[i] = u2f(pk & 0xFFFF0000u);
        ac2[i] = 0.f;
    }
    #pragma unroll
    for (int jb = 0; jb < 64; jb += 8) {
        float af[16], as_[16];
        #pragma unroll
        for (int u = 0; u < 8; ++u) {
            unsigned pk = EBpk[jb + u][cl];
            float ebf = u2f(pk << 16);
            float ebs = u2f(pk & 0xFFFF0000u);
            af[u * 2 + 0] = fmaf(eaf[0], ebf, 1.f);
            af[u * 2 + 1] = fmaf(eaf[1], ebf, 1.f);
            as_[u * 2 + 0] = fmaf(eas[0], ebs, 1.f);
            as_[u * 2 + 1] = fmaf(eas[1], ebs, 1.f);
        }
        float sg[16], lg[16];
        // volatile asm: statements keep mutual order -> 32 independent trans
        // issued back-to-back, hiding rcp/log latency under issue occupancy.
        #pragma unroll
        for (int u = 0; u < 16; ++u) {
            asm volatile("v_rcp_f32 %0, %1" : "=v"(sg[u]) : "v"(af[u]));
            asm volatile("v_log_f32 %0, %1" : "=v"(lg[u]) : "v"(as_[u]));
        }
        #pragma unroll
        for (int u = 0; u < 16; ++u)
            ac2[u & 1] = fmaf(sg[u], lg[u], ac2[u & 1]);
    }
    float s1 = 0.f, s2 = 0.f;
    #pragma unroll
    for (int i = 0; i < 2; ++i) {
        int d = h * 32 + slot * 2 + i;                // global dst row
        unsigned pk = EBpk[d][cl];
        float ebf = u2f(pk << 16);
        float ebs = u2f(pk & 0xFFFF0000u);
        float sg = __builtin_amdgcn_rcpf(fmaf(eaf[i], ebf, 1.f));
        float lg = __builtin_amdgcn_logf(fmaf(eas[i], ebs, 1.f));
        float v = (ac2[i] - sg * lg) * LN2;           // exact self-cancel
        agg_out[(size_t)(nbase + d) * D + c] = v;
        s1 += v; s2 += v * v;
    }
    stats_tree(EApk, EBpk, cl, slot, c, s1, s2, sacc_out);
}

// ---------------------------------------------------------------------------
// final: BN2 + residual (x1 recomputed from agg1) + relu -> out.
// Swizzled so the block for sample s runs on XCD s%8.
// ---------------------------------------------------------------------------
__global__ __launch_bounds__(256) void final_bn(
    const float* __restrict__ x0, const float* __restrict__ agg1,
    const float* __restrict__ agg2, const float* __restrict__ sacc,
    const float* __restrict__ gm1, const float* __restrict__ bt1,
    const float* __restrict__ gm2, const float* __restrict__ bt2,
    float* __restrict__ outp)
{
    const int tid = threadIdx.x;
    __shared__ float bnA[128], bnB[128], bn2A[128], bn2B[128];
    if (tid < 128) {
        const float inv = 1.f / NN;
        float mu = sacc[tid] * inv;
        float var = sacc[128 + tid] * inv - mu * mu;
        float rs = rsqrtf(var + EPSF);
        float A = rs * gm1[tid];
        bnA[tid] = A;
        bnB[tid] = fmaf(-mu, A, bt1[tid]);
        float mu2 = sacc[256 + tid] * inv;
        float var2 = sacc[384 + tid] * inv - mu2 * mu2;
        float rs2 = rsqrtf(var2 + EPSF);
        float A2 = rs2 * gm2[tid];
        bn2A[tid] = A2;
        bn2B[tid] = fmaf(-mu2, A2, bt2[tid]);
    }
    __syncthreads();
    const int bid = blockIdx.x;
    const int s = ((bid >> 5) << 3) + (bid & 7);
    const int inner = (bid >> 3) & 3;
    const int t = (s * 4 + inner) * 256 + tid;
    const int n = t >> 4, c8 = (t & 15) * 8;
    size_t off = (size_t)n * D + c8;
    float o[8];
    #pragma unroll
    for (int hh = 0; hh < 2; ++hh) {
        float4 g2 = *(const float4*)&agg2[off + hh * 4];
        float4 g1 = *(const float4*)&agg1[off + hh * 4];
        float4 xv = *(const float4*)&x0[off + hh * 4];
        int cc = c8 + hh * 4;
        o[hh*4+0] = fmaxf(0.f, fmaf(g2.x, bn2A[cc+0], bn2B[cc+0]) +
                    fmaxf(0.f, fmaf(g1.x, bnA[cc+0], bnB[cc+0]) + xv.x));
        o[hh*4+1] = fmaxf(0.f, fmaf(g2.y, bn2A[cc+1], bn2B[cc+1]) +
                    fmaxf(0.f, fmaf(g1.y, bnA[cc+1], bnB[cc+1]) + xv.y));
        o[hh*4+2] = fmaxf(0.f, fmaf(g2.z, bn2A[cc+2], bn2B[cc+2]) +
                    fmaxf(0.f, fmaf(g1.z, bnA[cc+2], bnB[cc+2]) + xv.z));
        o[hh*4+3] = fmaxf(0.f, fmaf(g2.w, bn2A[cc+3], bn2B[cc+3]) +
                    fmaxf(0.f, fmaf(g1.w, bnA[cc+3], bnB[cc+3]) + xv.w));
    }
    *(float4*)&outp[off]     = *(float4*)&o[0];
    *(float4*)&outp[off + 4] = *(float4*)&o[4];
}

// ---------------------------------------------------------------------------
extern "C" void kernel_launch(void* const* d_in, const int* in_sizes, int n_in,
                              void* d_out, int out_size, void* d_ws, size_t ws_size,
                              hipStream_t stream) {
    const float* x0      = (const float*)d_in[0];
    const float* centers = (const float*)d_in[1];
    // d_in[2], d_in[3]: edge lists — clique structure is deterministic, unused.
    const float* Wf1 = (const float*)d_in[4];
    const float* bf1 = (const float*)d_in[5];
    const float* Ws1 = (const float*)d_in[6];
    const float* bs1 = (const float*)d_in[7];
    const float* gm1 = (const float*)d_in[8];
    const float* bt1 = (const float*)d_in[9];
    const float* Wf2 = (const float*)d_in[10];
    const float* bf2 = (const float*)d_in[11];
    const float* Ws2 = (const float*)d_in[12];
    const float* bs2 = (const float*)d_in[13];
    const float* gm2 = (const float*)d_in[14];
    const float* bt2 = (const float*)d_in[15];

    const size_t ND = (size_t)NN * D;              // 1048576
    float* agg1 = (float*)d_ws;                    // ND
    float* agg2 = agg1 + ND;                       // ND
    float* sacc = agg1 + 2 * ND;                   // 2 layers x 256
    float* outp = (float*)d_out;

    hipMemsetAsync(sacc, 0, 512 * sizeof(float), stream);

    prep_half<1><<<dim3(2048), dim3(256), 0, stream>>>(
        x0, agg1 /*unused*/, centers, Wf1, bf1, Ws1, bs1,
        gm1 /*unused*/, bt1 /*unused*/, sacc /*unused*/, agg1, sacc);

    prep_half<2><<<dim3(2048), dim3(256), 0, stream>>>(
        x0, agg1, centers, Wf2, bf2, Ws2, bs2,
        gm1, bt1, sacc, agg2, sacc + 256);

    final_bn<<<dim3(512), dim3(256), 0, stream>>>(
        x0, agg1, agg2, sacc, gm1, bt1, gm2, bt2, outp);
}